// Round 2
// baseline (1524.523 us; speedup 1.0000x reference)
//
#include <hip/hip_runtime.h>
#include <math.h>

#define NB 2
#define NY 360
#define NX 720
#define NZ 32
#define NPTS (NB*NY*NX*NZ)     // 16,588,800
#define NCOL (NB*NY*NX)        // 518,400

__device__ __forceinline__ int i4(int b,int y,int x,int z){ return (((b*NY)+y)*NX+x)*NZ+z; }
__device__ __forceinline__ int i3(int b,int y,int x){ return ((b*NY)+y)*NX+x; }

#define F_RAD   6371000.0f
#define F_OMEGA 7.292e-5f
#define F_CP    1004.0f
#define F_DLAT  ((float)(M_PI/360.0))                 /* == dlon */
#define F_DYR   ((float)(M_PI/360.0*6371000.0))      /* dlat*RAD */
#define F_HPI   ((float)(M_PI/2.0))

// -------------------- kernel 1: div_h = du/dx + dv/dy --------------------
__global__ __launch_bounds__(256) void k_divh(const float* __restrict__ u,
                                              const float* __restrict__ v,
                                              float* __restrict__ divh) {
  int gid = blockIdx.x*256 + threadIdx.x;          // exact: 64800*256 = NPTS
  int z  = gid & 31;
  int x  = (gid >> 5) % NX;
  int by = gid / (NX*NZ);
  int y  = by % NY;
  int b  = by / NY;
  float lat = -F_HPI + (y+0.5f)*F_DLAT;
  float cl  = cosf(lat);
  float invdx = 0.5f/(F_DLAT*F_RAD*cl);
  int xp = (x==NX-1)?0:x+1, xm = (x==0)?NX-1:x-1;
  float dudx = (u[i4(b,y,xp,z)] - u[i4(b,y,xm,z)]) * invdx;
  float dvdy;
  if (y == 0)          dvdy = (v[i4(b,1,x,z)]    - v[i4(b,0,x,z)])    * (1.0f/F_DYR);
  else if (y == NY-1)  dvdy = (v[i4(b,NY-1,x,z)] - v[i4(b,NY-2,x,z)]) * (1.0f/F_DYR);
  else                 dvdy = (v[i4(b,y+1,x,z)]  - v[i4(b,y-1,x,z)])  * (0.5f/F_DYR);
  divh[gid] = dudx + dvdy;
}

// -------------------- kernel 2: all raw tendencies --------------------
// 256 threads = 8 columns x 32 z-lanes. Vertical scans via wave shuffles (width 32).
__global__ __launch_bounds__(256) void k_tend(
    const float* __restrict__ u, const float* __restrict__ v,
    const float* __restrict__ T, const float* __restrict__ ps,
    const float* __restrict__ Rp, const float* __restrict__ divh,
    float* __restrict__ du, float* __restrict__ dv,
    float* __restrict__ dT, float* __restrict__ dps) {
  const int tid = threadIdx.x;
  const int z   = tid & 31;
  const int col = blockIdx.x*8 + (tid>>5);         // exact: 64800*8 = NCOL
  const int x = col % NX;
  const int y = (col / NX) % NY;
  const int b = col / (NX*NY);
  const float R = Rp[0];

  const int xp = (x==NX-1)?0:x+1, xm = (x==0)?NX-1:x-1;
  const int ycm = (y>0)? y-1 : 0;
  const int ycp = (y<NY-1)? y+1 : NY-1;
  const bool y0 = (y==0), yN = (y==NY-1);

  const float lat  = -F_HPI + (y+0.5f)*F_DLAT;
  const float cl   = cosf(lat);
  const float fcor = 2.0f*F_OMEGA*sinf(lat);
  const float sx     = F_DLAT*F_RAD*cl;
  const float invdx  = 0.5f/sx;
  const float inv2dy = 0.5f/F_DYR;
  const float inv1dy = 1.0f/F_DYR;
  const float invsx2 = 1.0f/(sx*sx);
  const float invsy2 = 1.0f/(F_DYR*F_DYR);
  const float bk  = (z + 0.5f)/32.0f;
  const float dsv = 1.0f/32.0f;

  const int ic  = i4(b,y,x,z),   ixp = i4(b,y,xp,z), ixm = i4(b,y,xm,z);
  const int iyp = i4(b,ycp,x,z), iym = i4(b,ycm,x,z);

  const float uc=u[ic], uxp=u[ixp], uxm=u[ixm], uyp=u[iyp], uym=u[iym];
  const float vc=v[ic], vxp=v[ixp], vxm=v[ixm], vyp=v[iyp], vym=v[iym];
  const float Tc=T[ic], Txp=T[ixp], Txm=T[ixm], Typ=T[iyp], Tym=T[iym];
  const float Dc=divh[ic], Dxp=divh[ixp], Dxm=divh[ixm], Dyp=divh[iyp], Dym=divh[iym];
  const float psc=ps[i3(b,y,x)],   psxp=ps[i3(b,y,xp)], psxm=ps[i3(b,y,xm)];
  const float psyp=ps[i3(b,ycp,x)], psym=ps[i3(b,ycm,x)];

  auto dfy = [&](float fc_, float fyp_, float fym_) -> float {
    if (y0) return (fyp_ - fc_) * inv1dy;
    if (yN) return (fc_ - fym_) * inv1dy;
    return (fyp_ - fym_) * inv2dy;
  };
  auto lap = [&](float fc_, float fxp_, float fxm_, float fyp_, float fym_) -> float {
    float d2x = (fxp_ + fxm_ - 2.0f*fc_) * invsx2;
    float d2y = (y0||yN) ? 0.0f : (fyp_ + fym_ - 2.0f*fc_) * invsy2;
    return d2x + d2y;
  };
  auto sufscan = [&](float vv) -> float {   // vv[z] = sum_{j>=z}
    #pragma unroll
    for (int d=1; d<32; d<<=1) { float t = __shfl_down(vv, d, 32); if (z+d<32) vv += t; }
    return vv;
  };
  auto prescan = [&](float vv) -> float {   // vv[z] = sum_{j<=z}
    #pragma unroll
    for (int d=1; d<32; d<<=1) { float t = __shfl_up(vv, d, 32); if (z>=d) vv += t; }
    return vv;
  };
  auto vg = [&](float fc_) -> float {       // d/dsigma
    float fzp = __shfl_down(fc_,1,32), fzm = __shfl_up(fc_,1,32);
    if (z==0)  return (fzp - fc_) * 32.0f;
    if (z==31) return (fc_ - fzm) * 32.0f;
    return (fzp - fzm) * 16.0f;
  };

  // hydrostatic geopotential (suffix sum of R*T*ds/b) for the 5 stencil columns
  const float rz = dsv / bk;
  const float phic  = sufscan(R*Tc*rz);
  const float phixp = sufscan(R*Txp*rz);
  const float phixm = sufscan(R*Txm*rz);
  const float phiyp = sufscan(R*Typ*rz);
  const float phiym = sufscan(R*Tym*rz);

  const float dudx = (uxp-uxm)*invdx, dvdx = (vxp-vxm)*invdx, dTdx = (Txp-Txm)*invdx;
  const float dphidx = (phixp-phixm)*invdx;
  const float dudy = dfy(uc,uyp,uym), dvdy_ = dfy(vc,vyp,vym), dTdy = dfy(Tc,Typ,Tym);
  const float dphidy = dfy(phic,phiyp,phiym);
  const float dpsdx = (psxp-psxm)*invdx, dpsdy = dfy(psc,psyp,psym);
  const float gdivx = (Dxp-Dxm)*invdx,  gdivy = dfy(Dc,Dyp,Dym);

  // mass continuity / sigma_dot
  const float mass = Dc*psc + uc*dpsdx + vc*dpsdy;
  float Ipre = prescan(mass) * dsv;
  const float Itot = __shfl(Ipre, 31, 32);
  const float sigd = (bk*Itot - Ipre) / (psc + 1e-8f);

  const float vgu = vg(uc), vgv = vg(vc), vgT = vg(Tc);

  const float pfac = R*Tc*bk/(bk*psc + 1e-8f);
  const float pgfu = -dphidx - pfac*dpsdx;
  const float pgfv = -dphidy - pfac*dpsdy;
  const float cf2  = fmaxf(cl*cl, 0.01f);
  const float nudiv = 500000.0f*cf2, nuh = 100000.0f*cf2;
  const float lapu = lap(uc,uxp,uxm,uyp,uym);
  const float lapv = lap(vc,vxp,vxm,vyp,vym);
  const float lapT = lap(Tc,Txp,Txm,Typ,Tym);
  const float adiab = R*Tc/(bk*psc*F_CP + 1e-8f) * (sigd*psc);

  float dut = -(uc*dudx + vc*dudy)  - sigd*vgu + fcor*vc + pgfu + nuh*lapu - 1e-5f*uc + nudiv*gdivx;
  float dvt = -(uc*dvdx + vc*dvdy_) - sigd*vgv - fcor*uc + pgfv + nuh*lapv - 1e-5f*vc + nudiv*gdivy;
  float dTt = -(uc*dTdx + vc*dTdy)  - sigd*vgT + adiab + nuh*lapT;

  du[ic] = dut; dv[ic] = dvt; dT[ic] = dTt;
  if (z == 0) dps[i3(b,y,x)] = -Itot;
}

// -------------------- kernel 3: zero dqdt (it doubled as div_h scratch) ---
__global__ __launch_bounds__(256) void k_zero(float4* __restrict__ p) {
  p[blockIdx.x*256 + threadIdx.x] = make_float4(0.f,0.f,0.f,0.f);
}

// -------------------- polar filter helpers --------------------
__device__ __forceinline__ void filter_band(int y, int& k0, int& k1, bool& keepmode) {
  float lat = -F_HPI + (y+0.5f)*F_DLAT;
  float cut = fmaxf(360.0f*cosf(lat), 1.0f);
  int M = (int)floorf(cut);
  keepmode = (M <= 179);
  k0 = keepmode ? 0 : (M+1);
  k1 = keepmode ? M : 360;
}

// -------------------- kernel 4: polar filter, 4D fields ------------------
// One block per (b, y, z-quarter). out = lowpass (keep) or f - highpass (subtract);
// band size nk <= 180 either way. Direct DFT over the band with twiddle table
// (analysis) and per-x rotation recurrence (synthesis).
#define FKMAX 180
__global__ __launch_bounds__(384) void k_filter4(float* __restrict__ fld, float clipv) {
  __shared__ float  sf[NX][8];
  __shared__ float2 tw[NX];
  __shared__ float  sc[FKMAX][8];
  __shared__ float  ss[FKMAX][8];
  const int tid = threadIdx.x;
  const int zq  = blockIdx.x & 3;
  const int by  = blockIdx.x >> 2;   // 0..719
  const int y = by % NY, b = by / NY;
  float* base = fld + ((size_t)((b*NY+y)*NX))*NZ + zq*8;

  for (int t = tid; t < NX; t += 384) {
    float a = (float)t * (float)(2.0*M_PI/720.0);
    float sv, cv; sincosf(a, &sv, &cv);
    tw[t] = make_float2(cv, sv);
  }
  for (int t = tid; t < NX*8; t += 384) {
    int xx = t >> 3, zz = t & 7;
    sf[xx][zz] = base[(size_t)xx*NZ + zz];
  }
  int k0, k1; bool keepmode;
  filter_band(y, k0, k1, keepmode);
  const int nk = k1 - k0 + 1;
  __syncthreads();

  // ---- analysis: c_k[z], s_k[z] for band; thread = (kslot, zz), 2 k each
  const int zz = tid & 7;
  const int kslot = tid >> 3;        // 0..47
  for (int ksb = 0; ksb < nk; ksb += 96) {
    const int ra = ksb + 2*kslot;
    if (ra < nk) {
      const int ka = k0 + ra;
      const int kb = ka + 1;
      const bool vb = (ra+1 < nk);
      float aca=0.f, asa=0.f, acb=0.f, asb=0.f;
      int ia = 0, ib = 0;
      for (int xx = 0; xx < NX; ++xx) {
        const float fv = sf[xx][zz];
        const float2 ta = tw[ia];
        const float2 tb = tw[ib];
        aca = fmaf(fv, ta.x, aca); asa = fmaf(fv, ta.y, asa);
        acb = fmaf(fv, tb.x, acb); asb = fmaf(fv, tb.y, asb);
        ia += ka; if (ia >= NX) ia -= NX;
        ib += kb; if (ib >= NX) ib -= NX;
      }
      sc[ra][zz] = aca; ss[ra][zz] = asa;
      if (vb) { sc[ra+1][zz] = acb; ss[ra+1][zz] = asb; }
    }
  }
  __syncthreads();

  // ---- synthesis: thread owns x and x+360, all 8 z
  if (tid < 360) {
    const int x0 = tid, x1 = tid + 360;
    float acc0[8] = {0,0,0,0,0,0,0,0};
    float acc1[8] = {0,0,0,0,0,0,0,0};
    const int t0 = (x0 * k0) % NX;
    const int t1 = (x1 * k0) % NX;
    float c0 = tw[t0].x, s0 = tw[t0].y;
    float c1 = tw[t1].x, s1 = tw[t1].y;
    const float dc0 = tw[x0].x, dn0 = tw[x0].y;
    const float dc1 = tw[x1].x, dn1 = tw[x1].y;
    for (int kk = 0; kk < nk; ++kk) {
      const int k = k0 + kk;
      const float w = (k==0 || k==360) ? 1.0f : 2.0f;
      const float wc0 = w*c0, ws0 = w*s0, wc1 = w*c1, ws1 = w*s1;
      #pragma unroll
      for (int j = 0; j < 8; ++j) {
        const float cv = sc[kk][j], sv = ss[kk][j];
        acc0[j] = fmaf(cv, wc0, fmaf(sv, ws0, acc0[j]));
        acc1[j] = fmaf(cv, wc1, fmaf(sv, ws1, acc1[j]));
      }
      float n0 = c0*dc0 - s0*dn0; s0 = c0*dn0 + s0*dc0; c0 = n0;
      float n1 = c1*dc1 - s1*dn1; s1 = c1*dn1 + s1*dc1; c1 = n1;
    }
    const float inv = 1.0f/720.0f;
    #pragma unroll
    for (int j = 0; j < 8; ++j) {
      float o0 = keepmode ? acc0[j]*inv : sf[x0][j] - acc0[j]*inv;
      float o1 = keepmode ? acc1[j]*inv : sf[x1][j] - acc1[j]*inv;
      o0 = fminf(fmaxf(o0, -clipv), clipv);
      o1 = fminf(fmaxf(o1, -clipv), clipv);
      base[(size_t)x0*NZ + j] = o0;
      base[(size_t)x1*NZ + j] = o1;
    }
  }
}

// -------------------- kernel 5: polar filter for dpsdt (3D) ----------------
// 384 threads (synthesis needs >=360 threads — Round-1 bug was 256 here).
__global__ __launch_bounds__(384) void k_filter_ps(float* __restrict__ dps) {
  __shared__ float  f[NX];
  __shared__ float2 tw[NX];
  __shared__ float  sc[184], ss[184];
  const int tid = threadIdx.x;
  const int row = blockIdx.x;       // 0..719 = b*360+y
  const int y = row % NY;
  float* base = dps + (size_t)row*NX;
  for (int t = tid; t < NX; t += 384) {
    float a = (float)t * (float)(2.0*M_PI/720.0);
    float sv, cv; sincosf(a, &sv, &cv);
    tw[t] = make_float2(cv, sv);
    f[t] = base[t];
  }
  int k0, k1; bool keepmode;
  filter_band(y, k0, k1, keepmode);
  const int nk = k1 - k0 + 1;
  __syncthreads();

  if (tid < nk) {
    const int k = k0 + tid;
    float ac=0.f, as=0.f; int idx=0;
    for (int xx=0; xx<NX; ++xx) {
      const float fv = f[xx];
      const float2 t2 = tw[idx];
      ac = fmaf(fv, t2.x, ac); as = fmaf(fv, t2.y, as);
      idx += k; if (idx >= NX) idx -= NX;
    }
    sc[tid]=ac; ss[tid]=as;
  }
  __syncthreads();

  if (tid < 360) {
    const int x0 = tid, x1 = tid + 360;
    const int t0 = (x0 * k0) % NX;
    const int t1 = (x1 * k0) % NX;
    float c0 = tw[t0].x, s0 = tw[t0].y;
    float c1 = tw[t1].x, s1 = tw[t1].y;
    const float dc0 = tw[x0].x, dn0 = tw[x0].y;
    const float dc1 = tw[x1].x, dn1 = tw[x1].y;
    float a0 = 0.f, a1 = 0.f;
    for (int kk = 0; kk < nk; ++kk) {
      const int k = k0 + kk;
      const float w = (k==0 || k==360) ? 1.0f : 2.0f;
      a0 = fmaf(sc[kk], w*c0, fmaf(ss[kk], w*s0, a0));
      a1 = fmaf(sc[kk], w*c1, fmaf(ss[kk], w*s1, a1));
      float n0 = c0*dc0 - s0*dn0; s0 = c0*dn0 + s0*dc0; c0 = n0;
      float n1 = c1*dc1 - s1*dn1; s1 = c1*dn1 + s1*dc1; c1 = n1;
    }
    const float inv = 1.0f/720.0f;
    float o0 = keepmode ? a0*inv : f[x0] - a0*inv;
    float o1 = keepmode ? a1*inv : f[x1] - a1*inv;
    o0 = fminf(fmaxf(o0, -0.5f), 0.5f);
    o1 = fminf(fmaxf(o1, -0.5f), 0.5f);
    base[x0] = o0;
    base[x1] = o1;
  }
}

// -------------------- host --------------------
extern "C" void kernel_launch(void* const* d_in, const int* in_sizes, int n_in,
                              void* d_out, int out_size, void* d_ws, size_t ws_size,
                              hipStream_t stream) {
  (void)in_sizes; (void)n_in; (void)d_ws; (void)ws_size; (void)out_size;
  const float* u  = (const float*)d_in[0];
  const float* v  = (const float*)d_in[1];
  const float* T  = (const float*)d_in[2];
  // d_in[3] = q (unused, output is zeros)
  const float* ps = (const float*)d_in[4];
  // d_in[5] = g (unused by reference)
  const float* Rp = (const float*)d_in[6];

  float* out = (float*)d_out;
  float* du  = out;
  float* dv  = out + (size_t)NPTS;
  float* dT  = out + (size_t)2*NPTS;
  float* dq  = out + (size_t)3*NPTS;   // staged as div_h scratch, zeroed below
  float* dps = out + (size_t)4*NPTS;

  k_divh<<<NPTS/256, 256, 0, stream>>>(u, v, dq);
  k_tend<<<NCOL/8,   256, 0, stream>>>(u, v, T, ps, Rp, dq, du, dv, dT, dps);
  k_zero<<<NPTS/(256*4), 256, 0, stream>>>((float4*)dq);
  k_filter4<<<NB*NY*4, 384, 0, stream>>>(du, 0.02f);
  k_filter4<<<NB*NY*4, 384, 0, stream>>>(dv, 0.02f);
  k_filter4<<<NB*NY*4, 384, 0, stream>>>(dT, 0.01f);
  k_filter_ps<<<NB*NY, 384, 0, stream>>>(dps);
}

// Round 4
// 659.174 us; speedup vs baseline: 2.3128x; 2.3128x over previous
//
#include <hip/hip_runtime.h>
#include <math.h>

#define NB 2
#define NY 360
#define NX 720
#define NZ 32
#define NPTS (NB*NY*NX*NZ)     // 16,588,800
#define NCOL (NB*NY*NX)        // 518,400

__device__ __forceinline__ int i4(int b,int y,int x,int z){ return (((b*NY)+y)*NX+x)*NZ+z; }
__device__ __forceinline__ int i3(int b,int y,int x){ return ((b*NY)+y)*NX+x; }

#define F_RAD   6371000.0f
#define F_OMEGA 7.292e-5f
#define F_CP    1004.0f
#define F_DLAT  ((float)(M_PI/360.0))                 /* == dlon */
#define F_DYR   ((float)(M_PI/360.0*6371000.0))      /* dlat*RAD */
#define F_HPI   ((float)(M_PI/2.0))
#define TH      ((float)(2.0*M_PI/720.0))

// -------------------- kernel 1: div_h = du/dx + dv/dy --------------------
__global__ __launch_bounds__(256) void k_divh(const float* __restrict__ u,
                                              const float* __restrict__ v,
                                              float* __restrict__ divh) {
  int gid = blockIdx.x*256 + threadIdx.x;          // exact: 64800*256 = NPTS
  int z  = gid & 31;
  int x  = (gid >> 5) % NX;
  int by = gid / (NX*NZ);
  int y  = by % NY;
  int b  = by / NY;
  float lat = -F_HPI + (y+0.5f)*F_DLAT;
  float cl  = cosf(lat);
  float invdx = 0.5f/(F_DLAT*F_RAD*cl);
  int xp = (x==NX-1)?0:x+1, xm = (x==0)?NX-1:x-1;
  float dudx = (u[i4(b,y,xp,z)] - u[i4(b,y,xm,z)]) * invdx;
  float dvdy;
  if (y == 0)          dvdy = (v[i4(b,1,x,z)]    - v[i4(b,0,x,z)])    * (1.0f/F_DYR);
  else if (y == NY-1)  dvdy = (v[i4(b,NY-1,x,z)] - v[i4(b,NY-2,x,z)]) * (1.0f/F_DYR);
  else                 dvdy = (v[i4(b,y+1,x,z)]  - v[i4(b,y-1,x,z)])  * (0.5f/F_DYR);
  divh[gid] = dudx + dvdy;
}

// -------------------- kernel 2: all raw tendencies --------------------
__global__ __launch_bounds__(256) void k_tend(
    const float* __restrict__ u, const float* __restrict__ v,
    const float* __restrict__ T, const float* __restrict__ ps,
    const float* __restrict__ Rp, const float* __restrict__ divh,
    float* __restrict__ du, float* __restrict__ dv,
    float* __restrict__ dT, float* __restrict__ dps) {
  const int tid = threadIdx.x;
  const int z   = tid & 31;
  const int col = blockIdx.x*8 + (tid>>5);         // exact: 64800*8 = NCOL
  const int x = col % NX;
  const int y = (col / NX) % NY;
  const int b = col / (NX*NY);
  const float R = Rp[0];

  const int xp = (x==NX-1)?0:x+1, xm = (x==0)?NX-1:x-1;
  const int ycm = (y>0)? y-1 : 0;
  const int ycp = (y<NY-1)? y+1 : NY-1;
  const bool y0 = (y==0), yN = (y==NY-1);

  const float lat  = -F_HPI + (y+0.5f)*F_DLAT;
  const float cl   = cosf(lat);
  const float fcor = 2.0f*F_OMEGA*sinf(lat);
  const float sx     = F_DLAT*F_RAD*cl;
  const float invdx  = 0.5f/sx;
  const float inv2dy = 0.5f/F_DYR;
  const float inv1dy = 1.0f/F_DYR;
  const float invsx2 = 1.0f/(sx*sx);
  const float invsy2 = 1.0f/(F_DYR*F_DYR);
  const float bk  = (z + 0.5f)/32.0f;
  const float dsv = 1.0f/32.0f;

  const int ic  = i4(b,y,x,z),   ixp = i4(b,y,xp,z), ixm = i4(b,y,xm,z);
  const int iyp = i4(b,ycp,x,z), iym = i4(b,ycm,x,z);

  const float uc=u[ic], uxp=u[ixp], uxm=u[ixm], uyp=u[iyp], uym=u[iym];
  const float vc=v[ic], vxp=v[ixp], vxm=v[ixm], vyp=v[iyp], vym=v[iym];
  const float Tc=T[ic], Txp=T[ixp], Txm=T[ixm], Typ=T[iyp], Tym=T[iym];
  const float Dc=divh[ic], Dxp=divh[ixp], Dxm=divh[ixm], Dyp=divh[iyp], Dym=divh[iym];
  const float psc=ps[i3(b,y,x)],   psxp=ps[i3(b,y,xp)], psxm=ps[i3(b,y,xm)];
  const float psyp=ps[i3(b,ycp,x)], psym=ps[i3(b,ycm,x)];

  auto dfy = [&](float fc_, float fyp_, float fym_) -> float {
    if (y0) return (fyp_ - fc_) * inv1dy;
    if (yN) return (fc_ - fym_) * inv1dy;
    return (fyp_ - fym_) * inv2dy;
  };
  auto lap = [&](float fc_, float fxp_, float fxm_, float fyp_, float fym_) -> float {
    float d2x = (fxp_ + fxm_ - 2.0f*fc_) * invsx2;
    float d2y = (y0||yN) ? 0.0f : (fyp_ + fym_ - 2.0f*fc_) * invsy2;
    return d2x + d2y;
  };
  auto sufscan = [&](float vv) -> float {   // vv[z] = sum_{j>=z}
    #pragma unroll
    for (int d=1; d<32; d<<=1) { float t = __shfl_down(vv, d, 32); if (z+d<32) vv += t; }
    return vv;
  };
  auto prescan = [&](float vv) -> float {   // vv[z] = sum_{j<=z}
    #pragma unroll
    for (int d=1; d<32; d<<=1) { float t = __shfl_up(vv, d, 32); if (z>=d) vv += t; }
    return vv;
  };
  auto vg = [&](float fc_) -> float {       // d/dsigma
    float fzp = __shfl_down(fc_,1,32), fzm = __shfl_up(fc_,1,32);
    if (z==0)  return (fzp - fc_) * 32.0f;
    if (z==31) return (fc_ - fzm) * 32.0f;
    return (fzp - fzm) * 16.0f;
  };

  const float rz = dsv / bk;
  const float phic  = sufscan(R*Tc*rz);
  const float phixp = sufscan(R*Txp*rz);
  const float phixm = sufscan(R*Txm*rz);
  const float phiyp = sufscan(R*Typ*rz);
  const float phiym = sufscan(R*Tym*rz);

  const float dudx = (uxp-uxm)*invdx, dvdx = (vxp-vxm)*invdx, dTdx = (Txp-Txm)*invdx;
  const float dphidx = (phixp-phixm)*invdx;
  const float dudy = dfy(uc,uyp,uym), dvdy_ = dfy(vc,vyp,vym), dTdy = dfy(Tc,Typ,Tym);
  const float dphidy = dfy(phic,phiyp,phiym);
  const float dpsdx = (psxp-psxm)*invdx, dpsdy = dfy(psc,psyp,psym);
  const float gdivx = (Dxp-Dxm)*invdx,  gdivy = dfy(Dc,Dyp,Dym);

  const float mass = Dc*psc + uc*dpsdx + vc*dpsdy;
  float Ipre = prescan(mass) * dsv;
  const float Itot = __shfl(Ipre, 31, 32);
  const float sigd = (bk*Itot - Ipre) / (psc + 1e-8f);

  const float vgu = vg(uc), vgv = vg(vc), vgT = vg(Tc);

  const float pfac = R*Tc*bk/(bk*psc + 1e-8f);
  const float pgfu = -dphidx - pfac*dpsdx;
  const float pgfv = -dphidy - pfac*dpsdy;
  const float cf2  = fmaxf(cl*cl, 0.01f);
  const float nudiv = 500000.0f*cf2, nuh = 100000.0f*cf2;
  const float lapu = lap(uc,uxp,uxm,uyp,uym);
  const float lapv = lap(vc,vxp,vxm,vyp,vym);
  const float lapT = lap(Tc,Txp,Txm,Typ,Tym);
  const float adiab = R*Tc/(bk*psc*F_CP + 1e-8f) * (sigd*psc);

  float dut = -(uc*dudx + vc*dudy)  - sigd*vgu + fcor*vc + pgfu + nuh*lapu - 1e-5f*uc + nudiv*gdivx;
  float dvt = -(uc*dvdx + vc*dvdy_) - sigd*vgv - fcor*uc + pgfv + nuh*lapv - 1e-5f*vc + nudiv*gdivy;
  float dTt = -(uc*dTdx + vc*dTdy)  - sigd*vgT + adiab + nuh*lapT;

  du[ic] = dut; dv[ic] = dvt; dT[ic] = dTt;
  if (z == 0) dps[i3(b,y,x)] = -Itot;
}

// -------------------- kernel 3: zero dqdt --------------------
__global__ __launch_bounds__(256) void k_zero(float4* __restrict__ p) {
  p[blockIdx.x*256 + threadIdx.x] = make_float4(0.f,0.f,0.f,0.f);
}

// -------------------- polar filter helpers --------------------
__device__ __forceinline__ void filter_band(int y, int& k0, int& k1, bool& keepmode) {
  float lat = -F_HPI + (y+0.5f)*F_DLAT;
  float cut = fmaxf(360.0f*cosf(lat), 1.0f);
  int M = (int)floorf(cut);
  keepmode = (M <= 179);
  k0 = keepmode ? 0 : (M+1);
  k1 = keepmode ? M : 360;
}

// -------------------- kernel 4: folded-DFT polar filter, 3 fields ---------
// Quarter-fold: x = x' + 180*j. e^{i*th*k*(x'+180j)} = e^{i*th*k*x'} * (-i)^{(k&3)*j}.
// Analysis over 180 x' with folded inputs (S0,S2 real for k even; A-+iB for odd).
// Synthesis accumulates H_r = sum_{k==r (4)} w*(ac*cos+as*sin) (and the sin-phase
// partner for odd r) and combines across residues. Synthesis phasor rotates
// FORWARD by 4*x*theta per k-step (Round-3 bug was backward rotation).
__global__ __launch_bounds__(384) void k_filter4b(
    float* __restrict__ du, float* __restrict__ dv, float* __restrict__ dT) {
  __shared__ float S0[180][8];
  __shared__ float S2[180][8];
  __shared__ float AB[180][8][2];     // interleaved A,B
  __shared__ float SD[180][8][2];     // w*(c_k, s_k) per band index, per z

  const int tid  = threadIdx.x;
  const int zq   = blockIdx.x & 3;
  const int rest = blockIdx.x >> 2;
  const int by   = rest % (NB*NY);
  const int fld  = rest / (NB*NY);
  const int y = by % NY, b = by / NY;
  float* fptr = (fld==0)? du : (fld==1)? dv : dT;
  const float clipv = (fld==2)? 0.01f : 0.02f;
  float* base = fptr + ((size_t)(b*NY+y)*NX)*NZ + zq*8;

  int k0, k1; bool keep;
  filter_band(y, k0, k1, keep);

  // ---- load + fold ----
  if (tid < 360) {
    const int x  = tid % 180;
    const int zh = tid / 180;                       // 0/1 -> z offset 4*zh
    const float4 q0 = *(const float4*)(base + (size_t)(x      )*NZ + zh*4);
    const float4 q1 = *(const float4*)(base + (size_t)(x + 180)*NZ + zh*4);
    const float4 q2 = *(const float4*)(base + (size_t)(x + 360)*NZ + zh*4);
    const float4 q3 = *(const float4*)(base + (size_t)(x + 540)*NZ + zh*4);
    float4 s0v, s2v, av, bv;
    s0v.x=q0.x+q1.x+q2.x+q3.x; s2v.x=q0.x-q1.x+q2.x-q3.x; av.x=q0.x-q2.x; bv.x=q1.x-q3.x;
    s0v.y=q0.y+q1.y+q2.y+q3.y; s2v.y=q0.y-q1.y+q2.y-q3.y; av.y=q0.y-q2.y; bv.y=q1.y-q3.y;
    s0v.z=q0.z+q1.z+q2.z+q3.z; s2v.z=q0.z-q1.z+q2.z-q3.z; av.z=q0.z-q2.z; bv.z=q1.z-q3.z;
    s0v.w=q0.w+q1.w+q2.w+q3.w; s2v.w=q0.w-q1.w+q2.w-q3.w; av.w=q0.w-q2.w; bv.w=q1.w-q3.w;
    *(float4*)&S0[x][zh*4] = s0v;
    *(float4*)&S2[x][zh*4] = s2v;
    *(float4*)&AB[x][zh*4+0][0] = make_float4(av.x, bv.x, av.y, bv.y);
    *(float4*)&AB[x][zh*4+2][0] = make_float4(av.z, bv.z, av.w, bv.w);
  }
  __syncthreads();

  // ---- analysis: thread = (ks 0..95, z-pair 0..3). Even-k waves: ks<48. ----
  {
    const int zz2 = tid & 3;
    const int ks  = tid >> 2;          // 0..95
    const int zA  = 2*zz2;
    const bool isodd = (ks >= 48);
    const int m = isodd ? ks - 48 : ks;
    const int kfirst = k0 + ((k0 & 1) ^ (isodd ? 1 : 0));
    const int ka = kfirst + 2*m;
    const int kb = ka + 96;
    if (ka <= k1) {
      float dc1, ds1, dc2, ds2;
      sincosf((float)ka * TH, &ds1, &dc1);
      sincosf((float)kb * TH, &ds2, &dc2);
      float c1 = 1.f, s1 = 0.f, c2 = 1.f, s2 = 0.f;
      float cA0=0,sA0=0,cA1=0,sA1=0, cB0=0,sB0a=0,cB1=0,sB1a=0;
      const bool vb = (kb <= k1);
      if (!isodd) {
        const float* Sp = ((ka & 3) == 0) ? &S0[0][0] : &S2[0][0];
        if (vb) {
          for (int x = 0; x < 180; ++x) {
            const float2 sv = *(const float2*)&Sp[x*8 + zA];
            cA0 = fmaf(sv.x, c1, cA0); sA0 = fmaf(sv.x, s1, sA0);
            cA1 = fmaf(sv.y, c1, cA1); sA1 = fmaf(sv.y, s1, sA1);
            cB0 = fmaf(sv.x, c2, cB0); sB0a = fmaf(sv.x, s2, sB0a);
            cB1 = fmaf(sv.y, c2, cB1); sB1a = fmaf(sv.y, s2, sB1a);
            float n1 = fmaf(c1, dc1, -s1*ds1); s1 = fmaf(s1, dc1, c1*ds1); c1 = n1;
            float n2 = fmaf(c2, dc2, -s2*ds2); s2 = fmaf(s2, dc2, c2*ds2); c2 = n2;
          }
        } else {
          for (int x = 0; x < 180; ++x) {
            const float2 sv = *(const float2*)&Sp[x*8 + zA];
            cA0 = fmaf(sv.x, c1, cA0); sA0 = fmaf(sv.x, s1, sA0);
            cA1 = fmaf(sv.y, c1, cA1); sA1 = fmaf(sv.y, s1, sA1);
            float n1 = fmaf(c1, dc1, -s1*ds1); s1 = fmaf(s1, dc1, c1*ds1); c1 = n1;
          }
        }
      } else {
        const float sg = ((ka & 3) == 1) ? 1.0f : -1.0f;   // kb same residue
        if (vb) {
          for (int x = 0; x < 180; ++x) {
            const float4 ab = *(const float4*)&AB[x][zA][0]; // A0,B0,A1,B1
            const float t0 = sg*ab.y, t1 = sg*ab.w;
            cA0 = fmaf(ab.x, c1, fmaf(t0, -s1, cA0)); sA0 = fmaf(ab.x, s1, fmaf(t0, c1, sA0));
            cA1 = fmaf(ab.z, c1, fmaf(t1, -s1, cA1)); sA1 = fmaf(ab.z, s1, fmaf(t1, c1, sA1));
            cB0 = fmaf(ab.x, c2, fmaf(t0, -s2, cB0)); sB0a = fmaf(ab.x, s2, fmaf(t0, c2, sB0a));
            cB1 = fmaf(ab.z, c2, fmaf(t1, -s2, cB1)); sB1a = fmaf(ab.z, s2, fmaf(t1, c2, sB1a));
            float n1 = fmaf(c1, dc1, -s1*ds1); s1 = fmaf(s1, dc1, c1*ds1); c1 = n1;
            float n2 = fmaf(c2, dc2, -s2*ds2); s2 = fmaf(s2, dc2, c2*ds2); c2 = n2;
          }
        } else {
          for (int x = 0; x < 180; ++x) {
            const float4 ab = *(const float4*)&AB[x][zA][0];
            const float t0 = sg*ab.y, t1 = sg*ab.w;
            cA0 = fmaf(ab.x, c1, fmaf(t0, -s1, cA0)); sA0 = fmaf(ab.x, s1, fmaf(t0, c1, sA0));
            cA1 = fmaf(ab.z, c1, fmaf(t1, -s1, cA1)); sA1 = fmaf(ab.z, s1, fmaf(t1, c1, sA1));
            float n1 = fmaf(c1, dc1, -s1*ds1); s1 = fmaf(s1, dc1, c1*ds1); c1 = n1;
          }
        }
      }
      const float wa = (ka == 0 || ka == 360) ? 1.0f : 2.0f;
      *(float4*)&SD[ka - k0][zA][0] = make_float4(wa*cA0, wa*sA0, wa*cA1, wa*sA1);
      if (vb) {
        const float wb = (kb == 0 || kb == 360) ? 1.0f : 2.0f;
        *(float4*)&SD[kb - k0][zA][0] = make_float4(wb*cB0, wb*sB0a, wb*cB1, wb*sB1a);
      }
    }
  }
  __syncthreads();

  // ---- synthesis: thread = (x' 0..179, z-half 0..1), 4 z each ----
  if (tid < 360) {
    const int x  = tid % 180;
    const int zh = tid / 180;
    float HreE[2][4]; float Hro[2][4]; float Hio[2][4];
    #pragma unroll
    for (int i = 0; i < 2; ++i)
      #pragma unroll
      for (int j = 0; j < 4; ++j) { HreE[i][j]=0.f; Hro[i][j]=0.f; Hio[i][j]=0.f; }

    const int m4 = (4*x) % 720;
    float dstep_s, dstep_c; sincosf((float)m4 * TH, &dstep_s, &dstep_c);

    // even residues r=0,2: only Re needed
    #pragma unroll
    for (int ri = 0; ri < 2; ++ri) {
      const int r = ri*2;
      const int kst = k0 + ((r - (k0 & 3) + 4) & 3);
      if (kst > k1) continue;
      int mm = (kst * x) % 720;
      float sv, cv; sincosf((float)mm * TH, &sv, &cv);
      for (int k = kst; k <= k1; k += 4) {
        const float4 d01 = *(const float4*)&SD[k - k0][zh*4 + 0][0];
        const float4 d23 = *(const float4*)&SD[k - k0][zh*4 + 2][0];
        HreE[ri][0] = fmaf(d01.x, cv, fmaf(d01.y, sv, HreE[ri][0]));
        HreE[ri][1] = fmaf(d01.z, cv, fmaf(d01.w, sv, HreE[ri][1]));
        HreE[ri][2] = fmaf(d23.x, cv, fmaf(d23.y, sv, HreE[ri][2]));
        HreE[ri][3] = fmaf(d23.z, cv, fmaf(d23.w, sv, HreE[ri][3]));
        float nc = fmaf(cv, dstep_c, -sv*dstep_s);   // forward rotation +4x*theta
        float ns = fmaf(sv, dstep_c,  cv*dstep_s);
        cv = nc; sv = ns;
      }
    }
    // odd residues r=1,3: Re and Im
    #pragma unroll
    for (int ri = 0; ri < 2; ++ri) {
      const int r = ri*2 + 1;
      const int kst = k0 + ((r - (k0 & 3) + 4) & 3);
      if (kst > k1) continue;
      int mm = (kst * x) % 720;
      float sv, cv; sincosf((float)mm * TH, &sv, &cv);
      for (int k = kst; k <= k1; k += 4) {
        const float4 d01 = *(const float4*)&SD[k - k0][zh*4 + 0][0];
        const float4 d23 = *(const float4*)&SD[k - k0][zh*4 + 2][0];
        Hro[ri][0] = fmaf(d01.x, cv, fmaf(d01.y, sv, Hro[ri][0]));
        Hio[ri][0] = fmaf(d01.y, cv, fmaf(-d01.x, sv, Hio[ri][0]));
        Hro[ri][1] = fmaf(d01.z, cv, fmaf(d01.w, sv, Hro[ri][1]));
        Hio[ri][1] = fmaf(d01.w, cv, fmaf(-d01.z, sv, Hio[ri][1]));
        Hro[ri][2] = fmaf(d23.x, cv, fmaf(d23.y, sv, Hro[ri][2]));
        Hio[ri][2] = fmaf(d23.y, cv, fmaf(-d23.x, sv, Hio[ri][2]));
        Hro[ri][3] = fmaf(d23.z, cv, fmaf(d23.w, sv, Hro[ri][3]));
        Hio[ri][3] = fmaf(d23.w, cv, fmaf(-d23.z, sv, Hio[ri][3]));
        float nc = fmaf(cv, dstep_c, -sv*dstep_s);   // forward rotation +4x*theta
        float ns = fmaf(sv, dstep_c,  cv*dstep_s);
        cv = nc; sv = ns;
      }
    }

    const float inv = 1.0f/720.0f;
    float o[4][4];
    float4 s0v, s2v, ab01, ab23;
    if (!keep) {
      s0v  = *(const float4*)&S0[x][zh*4];
      s2v  = *(const float4*)&S2[x][zh*4];
      ab01 = *(const float4*)&AB[x][zh*4+0][0];
      ab23 = *(const float4*)&AB[x][zh*4+2][0];
    }
    #pragma unroll
    for (int j = 0; j < 4; ++j) {
      const float h0  = HreE[0][j], h2 = HreE[1][j];
      const float h1r = Hro[0][j],  h1i = Hio[0][j];
      const float h3r = Hro[1][j],  h3i = Hio[1][j];
      float l0 = (h0 + h1r + h2 + h3r) * inv;
      float l1 = (h0 + h1i - h2 - h3i) * inv;
      float l2 = (h0 - h1r + h2 - h3r) * inv;
      float l3 = (h0 - h1i - h2 + h3i) * inv;
      if (!keep) {
        const float s0j = (j==0)?s0v.x:(j==1)?s0v.y:(j==2)?s0v.z:s0v.w;
        const float s2j = (j==0)?s2v.x:(j==1)?s2v.y:(j==2)?s2v.z:s2v.w;
        const float aj  = (j==0)?ab01.x:(j==1)?ab01.z:(j==2)?ab23.x:ab23.z;
        const float bj  = (j==0)?ab01.y:(j==1)?ab01.w:(j==2)?ab23.y:ab23.w;
        const float sp = 0.25f*(s0j + s2j), sm = 0.25f*(s0j - s2j);
        const float q0v = sp + 0.5f*aj, q2v = sp - 0.5f*aj;
        const float q1v = sm + 0.5f*bj, q3v = sm - 0.5f*bj;
        l0 = q0v - l0; l1 = q1v - l1; l2 = q2v - l2; l3 = q3v - l3;
      }
      o[0][j] = fminf(fmaxf(l0, -clipv), clipv);
      o[1][j] = fminf(fmaxf(l1, -clipv), clipv);
      o[2][j] = fminf(fmaxf(l2, -clipv), clipv);
      o[3][j] = fminf(fmaxf(l3, -clipv), clipv);
    }
    #pragma unroll
    for (int j = 0; j < 4; ++j) {
      *(float4*)(base + (size_t)(x + 180*j)*NZ + zh*4) =
          make_float4(o[j][0], o[j][1], o[j][2], o[j][3]);
    }
  }
}

// -------------------- kernel 5: polar filter for dpsdt (3D) ----------------
__global__ __launch_bounds__(384) void k_filter_ps(float* __restrict__ dps) {
  __shared__ float  f[NX];
  __shared__ float2 tw[NX];
  __shared__ float  sc[184], ss[184];
  const int tid = threadIdx.x;
  const int row = blockIdx.x;       // 0..719 = b*360+y
  const int y = row % NY;
  float* base = dps + (size_t)row*NX;
  for (int t = tid; t < NX; t += 384) {
    float a = (float)t * (float)(2.0*M_PI/720.0);
    float sv, cv; sincosf(a, &sv, &cv);
    tw[t] = make_float2(cv, sv);
    f[t] = base[t];
  }
  int k0, k1; bool keepmode;
  filter_band(y, k0, k1, keepmode);
  const int nk = k1 - k0 + 1;
  __syncthreads();

  if (tid < nk) {
    const int k = k0 + tid;
    float ac=0.f, as=0.f; int idx=0;
    for (int xx=0; xx<NX; ++xx) {
      const float fv = f[xx];
      const float2 t2 = tw[idx];
      ac = fmaf(fv, t2.x, ac); as = fmaf(fv, t2.y, as);
      idx += k; if (idx >= NX) idx -= NX;
    }
    sc[tid]=ac; ss[tid]=as;
  }
  __syncthreads();

  if (tid < 360) {
    const int x0 = tid, x1 = tid + 360;
    const int t0 = (x0 * k0) % NX;
    const int t1 = (x1 * k0) % NX;
    float c0 = tw[t0].x, s0 = tw[t0].y;
    float c1 = tw[t1].x, s1 = tw[t1].y;
    const float dc0 = tw[x0].x, dn0 = tw[x0].y;
    const float dc1 = tw[x1].x, dn1 = tw[x1].y;
    float a0 = 0.f, a1 = 0.f;
    for (int kk = 0; kk < nk; ++kk) {
      const int k = k0 + kk;
      const float w = (k==0 || k==360) ? 1.0f : 2.0f;
      a0 = fmaf(sc[kk], w*c0, fmaf(ss[kk], w*s0, a0));
      a1 = fmaf(sc[kk], w*c1, fmaf(ss[kk], w*s1, a1));
      float n0 = c0*dc0 - s0*dn0; s0 = c0*dn0 + s0*dc0; c0 = n0;
      float n1 = c1*dc1 - s1*dn1; s1 = c1*dn1 + s1*dc1; c1 = n1;
    }
    const float inv = 1.0f/720.0f;
    float o0 = keepmode ? a0*inv : f[x0] - a0*inv;
    float o1 = keepmode ? a1*inv : f[x1] - a1*inv;
    o0 = fminf(fmaxf(o0, -0.5f), 0.5f);
    o1 = fminf(fmaxf(o1, -0.5f), 0.5f);
    base[x0] = o0;
    base[x1] = o1;
  }
}

// -------------------- host --------------------
extern "C" void kernel_launch(void* const* d_in, const int* in_sizes, int n_in,
                              void* d_out, int out_size, void* d_ws, size_t ws_size,
                              hipStream_t stream) {
  (void)in_sizes; (void)n_in; (void)d_ws; (void)ws_size; (void)out_size;
  const float* u  = (const float*)d_in[0];
  const float* v  = (const float*)d_in[1];
  const float* T  = (const float*)d_in[2];
  const float* ps = (const float*)d_in[4];
  const float* Rp = (const float*)d_in[6];

  float* out = (float*)d_out;
  float* du  = out;
  float* dv  = out + (size_t)NPTS;
  float* dT  = out + (size_t)2*NPTS;
  float* dq  = out + (size_t)3*NPTS;   // staged as div_h scratch, zeroed below
  float* dps = out + (size_t)4*NPTS;

  k_divh<<<NPTS/256, 256, 0, stream>>>(u, v, dq);
  k_tend<<<NCOL/8,   256, 0, stream>>>(u, v, T, ps, Rp, dq, du, dv, dT, dps);
  k_zero<<<NPTS/(256*4), 256, 0, stream>>>((float4*)dq);
  k_filter4b<<<3*NB*NY*4, 384, 0, stream>>>(du, dv, dT);
  k_filter_ps<<<NB*NY, 384, 0, stream>>>(dps);
}